// Round 8
// baseline (494.879 us; speedup 1.0000x reference)
//
#include <hip/hip_runtime.h>
#include <hip/hip_bf16.h>

#define KD 128   // KEY_DIM
#define VD 64    // VALUE_DIM
#define NA 256   // N_ACTIONS
#define NB 32    // B
#define LL 2048  // L

typedef __attribute__((ext_vector_type(8))) short bf16x8;
typedef __attribute__((ext_vector_type(4))) float f32x4;
typedef __attribute__((ext_vector_type(8))) unsigned short u16x8;
typedef __attribute__((ext_vector_type(4))) unsigned short u16x4;

static __device__ __forceinline__ unsigned short f2bf(float x) {
  __hip_bfloat16 h = __float2bfloat16(x);
  unsigned short u;
  __builtin_memcpy(&u, &h, 2);
  return u;
}

static __device__ __forceinline__ void stage16(const void* gsrc, void* ldst) {
  __builtin_amdgcn_global_load_lds(
      (const __attribute__((address_space(1))) void*)gsrc,
      (__attribute__((address_space(3))) void*)ldst, 16, 0, 0);
}

// ---------------------------------------------------------------
// K1: W2[n][a] = sum_k W[n][k][a]   (128 x 256 fp32)
// ---------------------------------------------------------------
__global__ __launch_bounds__(256) void fold_w(const float* __restrict__ W,
                                              float* __restrict__ W2) {
  const int idx = blockIdx.x * 256 + threadIdx.x;   // n*256 + a
  const int n = idx >> 8, a = idx & 255;
  const float* p = W + (long)n * (VD * NA) + a;
  float s = 0.f;
  #pragma unroll
  for (int k = 0; k < VD; ++k) s += p[k * NA];
  W2[idx] = s;
}

// ---------------------------------------------------------------
// K2: Tt[b][d][n] = sum_a W2[n][a] * V[b][a][d]   (bf16 out, transposed)
// ---------------------------------------------------------------
__global__ __launch_bounds__(128) void compute_t(const float* __restrict__ W2,
                                                 const float* __restrict__ V,
                                                 unsigned short* __restrict__ Tt) {
  const int n = threadIdx.x;
  const int d0 = blockIdx.x * 8;
  const int b = blockIdx.y;
  const float* vb = V + (long)b * NA * KD + d0;
  const float* w2p = W2 + n * NA;
  float acc[8] = {0.f, 0.f, 0.f, 0.f, 0.f, 0.f, 0.f, 0.f};
  for (int a = 0; a < NA; a += 4) {
    const float4 w = *(const float4*)(w2p + a);
    const float wq[4] = {w.x, w.y, w.z, w.w};
    #pragma unroll
    for (int q = 0; q < 4; ++q) {
      const float* vr = vb + (long)(a + q) * KD;
      #pragma unroll
      for (int j = 0; j < 8; ++j) acc[j] += wq[q] * vr[j];
    }
  }
  #pragma unroll
  for (int j = 0; j < 8; ++j)
    Tt[((long)b * KD + d0 + j) * KD + n] = f2bf(acc[j]);
}

// ---------------------------------------------------------------
// K3: key fp32 -> bf16, 8 elements/thread
// ---------------------------------------------------------------
__global__ __launch_bounds__(256) void cvt_key(const float* __restrict__ in,
                                               unsigned short* __restrict__ out) {
  const long i = ((long)blockIdx.x * 256 + threadIdx.x) * 8;
  const float4 f0 = *(const float4*)(in + i);
  const float4 f1 = *(const float4*)(in + i + 4);
  u16x8 r;
  r[0] = f2bf(f0.x); r[1] = f2bf(f0.y); r[2] = f2bf(f0.z); r[3] = f2bf(f0.w);
  r[4] = f2bf(f1.x); r[5] = f2bf(f1.y); r[6] = f2bf(f1.z); r[7] = f2bf(f1.w);
  *(u16x8*)(out + i) = r;
}

// ---------------------------------------------------------------
// K4: mem GEMM (single-tile-N): memB[b] = keyB[b] (2048x128) @ Tt[b]^T.
// 128x128 tile per block, K=128 staged once.
// ---------------------------------------------------------------
__global__ __launch_bounds__(256) void gemm_mem(const unsigned short* __restrict__ A,
                                                const unsigned short* __restrict__ Bm,
                                                unsigned short* __restrict__ C) {
  __shared__ unsigned short lds[32768];
  const int nper = gridDim.x >> 3;
  const int lg = (blockIdx.x & 7) * nper + (blockIdx.x >> 3);
  const int mt = lg & 15;
  const int b = lg >> 4;

  const int tid = threadIdx.x;
  const int lane = tid & 63, w = tid >> 6;
  const int l15 = lane & 15, lhi = lane >> 4;

  const unsigned short* gA = A + ((long)b * LL + mt * 128) * KD;
  const unsigned short* gB = Bm + (long)b * KD * KD;

  unsigned short* ldsA = lds;
  unsigned short* ldsB = lds + 16384;

  #pragma unroll
  for (int i = 0; i < 8; ++i) {
    const int addr = (w * 8 + i) * 1024 + lane * 16;
    const int row = addr >> 8;
    const int src = addr ^ ((row & 7) << 4);
    stage16((const char*)gA + src, (char*)ldsA + addr);
    stage16((const char*)gB + src, (char*)ldsB + addr);
  }
  __syncthreads();

  const int wr = w >> 1, wc = w & 1;
  f32x4 acc[4][4];
  #pragma unroll
  for (int i = 0; i < 4; ++i)
    #pragma unroll
    for (int j = 0; j < 4; ++j) acc[i][j] = f32x4{0.f, 0.f, 0.f, 0.f};

  #pragma unroll
  for (int ks = 0; ks < 4; ++ks) {
    const int kb = (ks * 32 + lhi * 8) * 2;
    bf16x8 av[4], bv[4];
    #pragma unroll
    for (int mf = 0; mf < 4; ++mf) {
      const int row = wr * 64 + mf * 16 + l15;
      const int byte = (row * 256 + kb) ^ ((row & 7) << 4);
      av[mf] = *(const bf16x8*)((const char*)ldsA + byte);
    }
    #pragma unroll
    for (int nf = 0; nf < 4; ++nf) {
      const int row = wc * 64 + nf * 16 + l15;
      const int byte = (row * 256 + kb) ^ ((row & 7) << 4);
      bv[nf] = *(const bf16x8*)((const char*)ldsB + byte);
    }
    #pragma unroll
    for (int mf = 0; mf < 4; ++mf)
      #pragma unroll
      for (int nf = 0; nf < 4; ++nf)
        acc[mf][nf] = __builtin_amdgcn_mfma_f32_16x16x32_bf16(bv[nf], av[mf],
                                                              acc[mf][nf], 0, 0, 0);
  }

  const long row0 = (long)b * LL + mt * 128 + wr * 64;
  const int col0 = wc * 64;
  #pragma unroll
  for (int mf = 0; mf < 4; ++mf)
    #pragma unroll
    for (int nf = 0; nf < 4; ++nf) {
      const long r = row0 + mf * 16 + l15;
      const int c = col0 + nf * 16 + lhi * 4;
      u16x4 v;
      #pragma unroll
      for (int i = 0; i < 4; ++i) v[i] = f2bf(acc[mf][nf][i]);
      *(u16x4*)(C + r * KD + c) = v;
    }
}

// ---------------------------------------------------------------
// K5: q GEMM, 256x256 tile per 512-thread block (8 waves, 2M x 4N,
// wave tile 128x64). B panel (64 KB) staged in LDS; A fragments read
// DIRECTLY global->VGPR in the ks loop (A panel is L2-hot; ~4x L2
// redundancy costs nothing vs HBM). LDS=64 KB + VGPR<=128 gives
// 2 blocks/CU: block g+1 stages/computes while block g's 256 KB store
// drain completes -> removes the per-generation pipeline bubble.
// Cached dwordx4 epilogue (nt stores measured -10 us twice).
// ---------------------------------------------------------------
__global__ __launch_bounds__(512, 4) void gemm_q(const unsigned short* __restrict__ A,
                                                 const unsigned short* __restrict__ Bm,
                                                 float* __restrict__ C) {
  __shared__ unsigned short ldsB[32768];  // B panel 64 KB

  // 2048 blocks: xcd = bid % 8 owns 256 logical = 4 whole batches
  const int lg = (blockIdx.x & 7) * 256 + (blockIdx.x >> 3);
  const int nt = lg & 7;           // fastest: 8 col-tiles share batch B panel
  const int mt = (lg >> 3) & 7;
  const int b = lg >> 6;

  const int tid = threadIdx.x;
  const int lane = tid & 63, w = tid >> 6;     // 8 waves
  const int l15 = lane & 15, lhi = lane >> 4;
  const int wrM = w >> 2;                      // 0..1 : 128-row block
  const int wcN = w & 3;                       // 0..3 : 64-col block

  const unsigned short* gA = A + ((long)b * LL + mt * 256) * KD;
  const unsigned short* gB = Bm + ((long)b * LL + nt * 256) * KD;

  // stage B panel; LDS dest linear, global src inverse-swizzled
  #pragma unroll
  for (int i = 0; i < 8; ++i) {
    const int addr = i * 8192 + tid * 16;  // byte offset in panel (64 KB / 8)
    const int row = addr >> 8;             // 256 B per row
    const int src = addr ^ ((row & 7) << 4);
    stage16((const char*)gB + src, (char*)ldsB + addr);
  }
  __syncthreads();

  f32x4 acc[8][4];
  #pragma unroll
  for (int i = 0; i < 8; ++i)
    #pragma unroll
    for (int j = 0; j < 4; ++j) acc[i][j] = f32x4{0.f, 0.f, 0.f, 0.f};

  #pragma unroll
  for (int ks = 0; ks < 4; ++ks) {
    const int kcol = ks * 32 + lhi * 8;          // element offset in row
    const int kb = kcol * 2;                     // byte offset
    bf16x8 av[8], bv[4];
    #pragma unroll
    for (int mf = 0; mf < 8; ++mf) {
      const int row = wrM * 128 + mf * 16 + l15;
      av[mf] = *(const bf16x8*)(gA + (long)row * KD + kcol);  // global, L2-hot
    }
    #pragma unroll
    for (int nf = 0; nf < 4; ++nf) {
      const int row = wcN * 64 + nf * 16 + l15;
      const int byte = (row * 256 + kb) ^ ((row & 7) << 4);
      bv[nf] = *(const bf16x8*)((const char*)ldsB + byte);
    }
    // swapped operands: lane&15 = out row, (lane>>4)*4+reg = out col
    #pragma unroll
    for (int mf = 0; mf < 8; ++mf)
      #pragma unroll
      for (int nf = 0; nf < 4; ++nf)
        acc[mf][nf] = __builtin_amdgcn_mfma_f32_16x16x32_bf16(bv[nf], av[mf],
                                                              acc[mf][nf], 0, 0, 0);
  }

  // epilogue: cached dwordx4; L2 merges the 4-lane 64 B row segments
  const long row0 = (long)b * LL + mt * 256 + wrM * 128;
  const int col0 = nt * 256 + wcN * 64;
  #pragma unroll
  for (int mf = 0; mf < 8; ++mf)
    #pragma unroll
    for (int nf = 0; nf < 4; ++nf) {
      const long r = row0 + mf * 16 + l15;
      const int c = col0 + nf * 16 + lhi * 4;
      *(f32x4*)(C + r * LL + c) = acc[mf][nf];
    }
}

// ---------------------------------------------------------------
// launch
// ---------------------------------------------------------------
extern "C" void kernel_launch(void* const* d_in, const int* in_sizes, int n_in,
                              void* d_out, int out_size, void* d_ws, size_t ws_size,
                              hipStream_t stream) {
  const float* key = (const float*)d_in[0];  // (32, 2048, 128)
  const float* val = (const float*)d_in[1];  // (32, 256, 128)
  const float* wts = (const float*)d_in[2];  // (128, 64, 256)
  float* out = (float*)d_out;                // (32, 2048, 2048) fp32

  // workspace layout (total ~33.1 MiB)
  char* ws = (char*)d_ws;
  float* W2 = (float*)ws;                                        // 128 KiB
  unsigned short* Tt = (unsigned short*)(ws + 131072);           // 1 MiB
  unsigned short* keyB = (unsigned short*)(ws + 131072 + 1048576);            // 16 MiB
  unsigned short* memB = (unsigned short*)(ws + 131072 + 1048576 + 16777216); // 16 MiB

  fold_w<<<128, 256, 0, stream>>>(wts, W2);
  compute_t<<<dim3(16, NB), 128, 0, stream>>>(W2, val, Tt);
  cvt_key<<<4096, 256, 0, stream>>>(key, keyB);
  gemm_mem<<<16 * NB, 256, 0, stream>>>(keyB, Tt, memB);
  gemm_q<<<8 * 8 * NB, 512, 0, stream>>>(keyB, memB, out);
}

// Round 9
// 165.489 us; speedup vs baseline: 2.9904x; 2.9904x over previous
//
#include <hip/hip_runtime.h>
#include <hip/hip_bf16.h>

#define KD 128   // KEY_DIM
#define VD 64    // VALUE_DIM
#define NA 256   // N_ACTIONS
#define NB 32    // B
#define LL 2048  // L

typedef __attribute__((ext_vector_type(8))) short bf16x8;
typedef __attribute__((ext_vector_type(4))) float f32x4;
typedef __attribute__((ext_vector_type(8))) unsigned short u16x8;
typedef __attribute__((ext_vector_type(4))) unsigned short u16x4;

static __device__ __forceinline__ unsigned short f2bf(float x) {
  __hip_bfloat16 h = __float2bfloat16(x);
  unsigned short u;
  __builtin_memcpy(&u, &h, 2);
  return u;
}

static __device__ __forceinline__ void stage16(const void* gsrc, void* ldst) {
  __builtin_amdgcn_global_load_lds(
      (const __attribute__((address_space(1))) void*)gsrc,
      (__attribute__((address_space(3))) void*)ldst, 16, 0, 0);
}

// ---------------------------------------------------------------
// K1: W2[n][a] = sum_k W[n][k][a]   (128 x 256 fp32)
// ---------------------------------------------------------------
__global__ __launch_bounds__(256) void fold_w(const float* __restrict__ W,
                                              float* __restrict__ W2) {
  const int idx = blockIdx.x * 256 + threadIdx.x;   // n*256 + a
  const int n = idx >> 8, a = idx & 255;
  const float* p = W + (long)n * (VD * NA) + a;
  float s = 0.f;
  #pragma unroll
  for (int k = 0; k < VD; ++k) s += p[k * NA];
  W2[idx] = s;
}

// ---------------------------------------------------------------
// K2: Tt[b][d][n] = sum_a W2[n][a] * V[b][a][d]   (bf16 out, transposed)
// ---------------------------------------------------------------
__global__ __launch_bounds__(128) void compute_t(const float* __restrict__ W2,
                                                 const float* __restrict__ V,
                                                 unsigned short* __restrict__ Tt) {
  const int n = threadIdx.x;
  const int d0 = blockIdx.x * 8;
  const int b = blockIdx.y;
  const float* vb = V + (long)b * NA * KD + d0;
  const float* w2p = W2 + n * NA;
  float acc[8] = {0.f, 0.f, 0.f, 0.f, 0.f, 0.f, 0.f, 0.f};
  for (int a = 0; a < NA; a += 4) {
    const float4 w = *(const float4*)(w2p + a);
    const float wq[4] = {w.x, w.y, w.z, w.w};
    #pragma unroll
    for (int q = 0; q < 4; ++q) {
      const float* vr = vb + (long)(a + q) * KD;
      #pragma unroll
      for (int j = 0; j < 8; ++j) acc[j] += wq[q] * vr[j];
    }
  }
  #pragma unroll
  for (int j = 0; j < 8; ++j)
    Tt[((long)b * KD + d0 + j) * KD + n] = f2bf(acc[j]);
}

// ---------------------------------------------------------------
// K3: key fp32 -> bf16, 8 elements/thread
// ---------------------------------------------------------------
__global__ __launch_bounds__(256) void cvt_key(const float* __restrict__ in,
                                               unsigned short* __restrict__ out) {
  const long i = ((long)blockIdx.x * 256 + threadIdx.x) * 8;
  const float4 f0 = *(const float4*)(in + i);
  const float4 f1 = *(const float4*)(in + i + 4);
  u16x8 r;
  r[0] = f2bf(f0.x); r[1] = f2bf(f0.y); r[2] = f2bf(f0.z); r[3] = f2bf(f0.w);
  r[4] = f2bf(f1.x); r[5] = f2bf(f1.y); r[6] = f2bf(f1.z); r[7] = f2bf(f1.w);
  *(u16x8*)(out + i) = r;
}

// ---------------------------------------------------------------
// K4: mem GEMM (single-tile-N): memB[b] = keyB[b] (2048x128) @ Tt[b]^T.
// 128x128 tile per block, K=128 staged once.
// ---------------------------------------------------------------
__global__ __launch_bounds__(256) void gemm_mem(const unsigned short* __restrict__ A,
                                                const unsigned short* __restrict__ Bm,
                                                unsigned short* __restrict__ C) {
  __shared__ unsigned short lds[32768];
  const int nper = gridDim.x >> 3;
  const int lg = (blockIdx.x & 7) * nper + (blockIdx.x >> 3);
  const int mt = lg & 15;
  const int b = lg >> 4;

  const int tid = threadIdx.x;
  const int lane = tid & 63, w = tid >> 6;
  const int l15 = lane & 15, lhi = lane >> 4;

  const unsigned short* gA = A + ((long)b * LL + mt * 128) * KD;
  const unsigned short* gB = Bm + (long)b * KD * KD;

  unsigned short* ldsA = lds;
  unsigned short* ldsB = lds + 16384;

  #pragma unroll
  for (int i = 0; i < 8; ++i) {
    const int addr = (w * 8 + i) * 1024 + lane * 16;
    const int row = addr >> 8;
    const int src = addr ^ ((row & 7) << 4);
    stage16((const char*)gA + src, (char*)ldsA + addr);
    stage16((const char*)gB + src, (char*)ldsB + addr);
  }
  __syncthreads();

  const int wr = w >> 1, wc = w & 1;
  f32x4 acc[4][4];
  #pragma unroll
  for (int i = 0; i < 4; ++i)
    #pragma unroll
    for (int j = 0; j < 4; ++j) acc[i][j] = f32x4{0.f, 0.f, 0.f, 0.f};

  #pragma unroll
  for (int ks = 0; ks < 4; ++ks) {
    const int kb = (ks * 32 + lhi * 8) * 2;
    bf16x8 av[4], bv[4];
    #pragma unroll
    for (int mf = 0; mf < 4; ++mf) {
      const int row = wr * 64 + mf * 16 + l15;
      const int byte = (row * 256 + kb) ^ ((row & 7) << 4);
      av[mf] = *(const bf16x8*)((const char*)ldsA + byte);
    }
    #pragma unroll
    for (int nf = 0; nf < 4; ++nf) {
      const int row = wc * 64 + nf * 16 + l15;
      const int byte = (row * 256 + kb) ^ ((row & 7) << 4);
      bv[nf] = *(const bf16x8*)((const char*)ldsB + byte);
    }
    #pragma unroll
    for (int mf = 0; mf < 4; ++mf)
      #pragma unroll
      for (int nf = 0; nf < 4; ++nf)
        acc[mf][nf] = __builtin_amdgcn_mfma_f32_16x16x32_bf16(bv[nf], av[mf],
                                                              acc[mf][nf], 0, 0, 0);
  }

  const long row0 = (long)b * LL + mt * 128 + wr * 64;
  const int col0 = wc * 64;
  #pragma unroll
  for (int mf = 0; mf < 4; ++mf)
    #pragma unroll
    for (int nf = 0; nf < 4; ++nf) {
      const long r = row0 + mf * 16 + l15;
      const int c = col0 + nf * 16 + lhi * 4;
      u16x4 v;
      #pragma unroll
      for (int i = 0; i < 4; ++i) v[i] = f2bf(acc[mf][nf][i]);
      *(u16x4*)(C + r * KD + c) = v;
    }
}

// ---------------------------------------------------------------
// K5: q GEMM, B-resident mt-loop. 256 blocks (1/CU), block = (b, nt).
// B panel (256 cols x 128 K, 64 KB) staged once into LDS; loop over
// 8 mt tiles: compute 256x256 from LDS A-buf + B, then
//   barrier -> issue stage A(mt+1) -> issue 32 stores -> vmcnt(32)
// Loads precede stores in the VM queue, so vmcnt(32) (= this gen's
// stores left in flight) guarantees the 8 loads retired WITHOUT
// draining the store stream (in-order vmcnt retire). Raw s_barrier
// (NOT __syncthreads, which drains vmcnt to 0) + sched_barrier fences.
// Guaranteed HBM reads: 256 x (64 + 8*64) KB = 147 MB (vs 256 MB).
// Stage+compute hide under the ~10 us/gen store drain (the floor).
// ---------------------------------------------------------------
__global__ __launch_bounds__(512, 2) void gemm_q(const unsigned short* __restrict__ A,
                                                 const unsigned short* __restrict__ Bm,
                                                 float* __restrict__ C) {
  __shared__ unsigned short ldsA[32768];  // A tile  64 KB (restaged per mt)
  __shared__ unsigned short ldsB[32768];  // B panel 64 KB (resident)

  // 256 blocks: xcd = bid % 8 owns 32 logical = 4 whole batches
  const int lg = (blockIdx.x & 7) * 32 + (blockIdx.x >> 3);
  const int nt = lg & 7;
  const int b = lg >> 3;

  const int tid = threadIdx.x;
  const int lane = tid & 63, w = tid >> 6;     // 8 waves
  const int l15 = lane & 15, lhi = lane >> 4;
  const int wrM = w >> 2;                      // 0..1 : 128-row block
  const int wcN = w & 3;                       // 0..3 : 64-col block

  const unsigned short* gB = Bm + ((long)b * LL + nt * 256) * KD;
  const unsigned short* gAb = A + (long)b * LL * KD;

  // ---- prologue: stage B panel + A(0); full drain ----
  #pragma unroll
  for (int i = 0; i < 8; ++i) {
    const int addr = i * 8192 + tid * 16;
    const int row = addr >> 8;
    const int src = addr ^ ((row & 7) << 4);
    stage16((const char*)gB + src, (char*)ldsB + addr);
    stage16((const char*)gAb + src, (char*)ldsA + addr);  // mt = 0
  }
  asm volatile("s_waitcnt vmcnt(0)" ::: "memory");
  __builtin_amdgcn_s_barrier();
  __builtin_amdgcn_sched_barrier(0);

  const int col0 = nt * 256 + wcN * 64;

  for (int mt = 0; mt < 8; ++mt) {
    // ---- compute 256x256 tile from ldsA + ldsB ----
    f32x4 acc[8][4];
    #pragma unroll
    for (int i = 0; i < 8; ++i)
      #pragma unroll
      for (int j = 0; j < 4; ++j) acc[i][j] = f32x4{0.f, 0.f, 0.f, 0.f};

    #pragma unroll
    for (int ks = 0; ks < 4; ++ks) {
      const int kb = (ks * 32 + lhi * 8) * 2;
      bf16x8 av[8], bv[4];
      #pragma unroll
      for (int mf = 0; mf < 8; ++mf) {
        const int row = wrM * 128 + mf * 16 + l15;
        const int byte = (row * 256 + kb) ^ ((row & 7) << 4);
        av[mf] = *(const bf16x8*)((const char*)ldsA + byte);
      }
      #pragma unroll
      for (int nf = 0; nf < 4; ++nf) {
        const int row = wcN * 64 + nf * 16 + l15;
        const int byte = (row * 256 + kb) ^ ((row & 7) << 4);
        bv[nf] = *(const bf16x8*)((const char*)ldsB + byte);
      }
      // swapped operands: lane&15 = out row, (lane>>4)*4+reg = out col
      #pragma unroll
      for (int mf = 0; mf < 8; ++mf)
        #pragma unroll
        for (int nf = 0; nf < 4; ++nf)
          acc[mf][nf] = __builtin_amdgcn_mfma_f32_16x16x32_bf16(bv[nf], av[mf],
                                                                acc[mf][nf], 0, 0, 0);
    }

    // all waves done reading ldsA (ds_reads retired before last MFMA issue)
    asm volatile("s_waitcnt lgkmcnt(0)" ::: "memory");
    __builtin_amdgcn_s_barrier();
    __builtin_amdgcn_sched_barrier(0);

    // ---- issue next A stage FIRST (oldest in VM queue) ----
    if (mt < 7) {
      const char* gA = (const char*)(gAb + (long)(mt + 1) * 256 * KD);
      #pragma unroll
      for (int i = 0; i < 8; ++i) {
        const int addr = i * 8192 + tid * 16;
        const int row = addr >> 8;
        const int src = addr ^ ((row & 7) << 4);
        stage16(gA + src, (char*)ldsA + addr);
      }
    }
    __builtin_amdgcn_sched_barrier(0);  // pin: loads before stores

    // ---- issue 32 cached dwordx4 stores (fire and forget) ----
    const long row0 = (long)b * LL + mt * 256 + wrM * 128;
    #pragma unroll
    for (int mf = 0; mf < 8; ++mf)
      #pragma unroll
      for (int nf = 0; nf < 4; ++nf) {
        const long r = row0 + mf * 16 + l15;
        const int c = col0 + nf * 16 + lhi * 4;
        *(f32x4*)(C + r * LL + c) = acc[mf][nf];
      }

    // wait: outstanding <= 32 => (prev leftovers + 8 loads) retired,
    // this generation's 32 stores still in flight.
    if (mt < 7) {
      asm volatile("s_waitcnt vmcnt(32)" ::: "memory");
      __builtin_amdgcn_sched_barrier(0);
      __builtin_amdgcn_s_barrier();
      __builtin_amdgcn_sched_barrier(0);
    }
  }
}

// ---------------------------------------------------------------
// launch
// ---------------------------------------------------------------
extern "C" void kernel_launch(void* const* d_in, const int* in_sizes, int n_in,
                              void* d_out, int out_size, void* d_ws, size_t ws_size,
                              hipStream_t stream) {
  const float* key = (const float*)d_in[0];  // (32, 2048, 128)
  const float* val = (const float*)d_in[1];  // (32, 256, 128)
  const float* wts = (const float*)d_in[2];  // (128, 64, 256)
  float* out = (float*)d_out;                // (32, 2048, 2048) fp32

  // workspace layout (total ~33.1 MiB)
  char* ws = (char*)d_ws;
  float* W2 = (float*)ws;                                        // 128 KiB
  unsigned short* Tt = (unsigned short*)(ws + 131072);           // 1 MiB
  unsigned short* keyB = (unsigned short*)(ws + 131072 + 1048576);            // 16 MiB
  unsigned short* memB = (unsigned short*)(ws + 131072 + 1048576 + 16777216); // 16 MiB

  fold_w<<<128, 256, 0, stream>>>(wts, W2);
  compute_t<<<dim3(16, NB), 128, 0, stream>>>(W2, val, Tt);
  cvt_key<<<4096, 256, 0, stream>>>(key, keyB);
  gemm_mem<<<16 * NB, 256, 0, stream>>>(keyB, Tt, memB);
  gemm_q<<<8 * NB, 512, 0, stream>>>(keyB, memB, out);
}

// Round 10
// 159.502 us; speedup vs baseline: 3.1027x; 1.0375x over previous
//
#include <hip/hip_runtime.h>
#include <hip/hip_bf16.h>

#define KD 128   // KEY_DIM
#define VD 64    // VALUE_DIM
#define NA 256   // N_ACTIONS
#define NB 32    // B
#define LL 2048  // L

typedef __attribute__((ext_vector_type(8))) short bf16x8;
typedef __attribute__((ext_vector_type(4))) float f32x4;
typedef __attribute__((ext_vector_type(8))) unsigned short u16x8;
typedef __attribute__((ext_vector_type(4))) unsigned short u16x4;

static __device__ __forceinline__ unsigned short f2bf(float x) {
  __hip_bfloat16 h = __float2bfloat16(x);
  unsigned short u;
  __builtin_memcpy(&u, &h, 2);
  return u;
}

static __device__ __forceinline__ void stage16(const void* gsrc, void* ldst) {
  __builtin_amdgcn_global_load_lds(
      (const __attribute__((address_space(1))) void*)gsrc,
      (__attribute__((address_space(3))) void*)ldst, 16, 0, 0);
}

// ---------------------------------------------------------------
// K1: W2[n][a] = sum_k W[n][k][a]   (128 x 256 fp32)
// ---------------------------------------------------------------
__global__ __launch_bounds__(256) void fold_w(const float* __restrict__ W,
                                              float* __restrict__ W2) {
  const int idx = blockIdx.x * 256 + threadIdx.x;   // n*256 + a
  const int n = idx >> 8, a = idx & 255;
  const float* p = W + (long)n * (VD * NA) + a;
  float s = 0.f;
  #pragma unroll
  for (int k = 0; k < VD; ++k) s += p[k * NA];
  W2[idx] = s;
}

// ---------------------------------------------------------------
// K2: Tt[b][d][n] = sum_a W2[n][a] * V[b][a][d]   (bf16 out, transposed)
// ---------------------------------------------------------------
__global__ __launch_bounds__(128) void compute_t(const float* __restrict__ W2,
                                                 const float* __restrict__ V,
                                                 unsigned short* __restrict__ Tt) {
  const int n = threadIdx.x;
  const int d0 = blockIdx.x * 8;
  const int b = blockIdx.y;
  const float* vb = V + (long)b * NA * KD + d0;
  const float* w2p = W2 + n * NA;
  float acc[8] = {0.f, 0.f, 0.f, 0.f, 0.f, 0.f, 0.f, 0.f};
  for (int a = 0; a < NA; a += 4) {
    const float4 w = *(const float4*)(w2p + a);
    const float wq[4] = {w.x, w.y, w.z, w.w};
    #pragma unroll
    for (int q = 0; q < 4; ++q) {
      const float* vr = vb + (long)(a + q) * KD;
      #pragma unroll
      for (int j = 0; j < 8; ++j) acc[j] += wq[q] * vr[j];
    }
  }
  #pragma unroll
  for (int j = 0; j < 8; ++j)
    Tt[((long)b * KD + d0 + j) * KD + n] = f2bf(acc[j]);
}

// ---------------------------------------------------------------
// K3 (fused cvt_key + gemm_mem): per block (b, mt of 16):
//  - reg-stage 128x128 fp32 key tile -> convert bf16 -> swizzled
//    ds_write_b128 into ldsA  AND  global-write keyB (byproduct).
//  - stage Tt[b] (32 KB) via global_load_lds (linear+inv-swz src).
//  - 128x128 MFMA tile -> memB.
// Removes cvt_key's separate 33.5 MB read pass + keyB re-read.
// ---------------------------------------------------------------
__global__ __launch_bounds__(256) void gemm_mem_f(const float* __restrict__ key,
                                                  const unsigned short* __restrict__ Tt,
                                                  unsigned short* __restrict__ keyB,
                                                  unsigned short* __restrict__ memB) {
  __shared__ unsigned short ldsA[16384];  // 32 KB
  __shared__ unsigned short ldsB[16384];  // 32 KB
  const int nper = gridDim.x >> 3;
  const int lg = (blockIdx.x & 7) * nper + (blockIdx.x >> 3);
  const int mt = lg & 15;
  const int b = lg >> 4;

  const int tid = threadIdx.x;
  const int lane = tid & 63, w = tid >> 6;
  const int l15 = lane & 15, lhi = lane >> 4;

  const float* gK = key + ((long)b * LL + mt * 128) * KD;
  unsigned short* gKB = keyB + ((long)b * LL + mt * 128) * KD;
  const unsigned short* gB = Tt + (long)b * KD * KD;

  // stage B (Tt) via gload_lds: linear LDS dest, inverse-swizzled src
  #pragma unroll
  for (int i = 0; i < 8; ++i) {
    const int addr = (w * 8 + i) * 1024 + lane * 16;
    const int row = addr >> 8;
    const int src = addr ^ ((row & 7) << 4);
    stage16((const char*)gB + src, (char*)ldsB + addr);
  }
  // reg-stage A: fp32 -> bf16, swizzled ds_write + keyB byproduct
  #pragma unroll
  for (int it = 0; it < 8; ++it) {
    const int idx = it * 256 + tid;     // 2048 groups of 8 elems
    const int row = idx >> 4;           // 0..127
    const int c8 = idx & 15;            // 16 groups per row
    const float4 f0 = *(const float4*)(gK + row * KD + c8 * 8);
    const float4 f1 = *(const float4*)(gK + row * KD + c8 * 8 + 4);
    u16x8 v;
    v[0] = f2bf(f0.x); v[1] = f2bf(f0.y); v[2] = f2bf(f0.z); v[3] = f2bf(f0.w);
    v[4] = f2bf(f1.x); v[5] = f2bf(f1.y); v[6] = f2bf(f1.z); v[7] = f2bf(f1.w);
    *(u16x8*)(gKB + row * KD + c8 * 8) = v;
    const int byte = (row * 256 + c8 * 16) ^ ((row & 7) << 4);
    *(u16x8*)((char*)ldsA + byte) = v;
  }
  __syncthreads();

  const int wr = w >> 1, wc = w & 1;
  f32x4 acc[4][4];
  #pragma unroll
  for (int i = 0; i < 4; ++i)
    #pragma unroll
    for (int j = 0; j < 4; ++j) acc[i][j] = f32x4{0.f, 0.f, 0.f, 0.f};

  #pragma unroll
  for (int ks = 0; ks < 4; ++ks) {
    const int kb = (ks * 32 + lhi * 8) * 2;
    bf16x8 av[4], bv[4];
    #pragma unroll
    for (int mf = 0; mf < 4; ++mf) {
      const int row = wr * 64 + mf * 16 + l15;
      const int byte = (row * 256 + kb) ^ ((row & 7) << 4);
      av[mf] = *(const bf16x8*)((const char*)ldsA + byte);
    }
    #pragma unroll
    for (int nf = 0; nf < 4; ++nf) {
      const int row = wc * 64 + nf * 16 + l15;
      const int byte = (row * 256 + kb) ^ ((row & 7) << 4);
      bv[nf] = *(const bf16x8*)((const char*)ldsB + byte);
    }
    #pragma unroll
    for (int mf = 0; mf < 4; ++mf)
      #pragma unroll
      for (int nf = 0; nf < 4; ++nf)
        acc[mf][nf] = __builtin_amdgcn_mfma_f32_16x16x32_bf16(bv[nf], av[mf],
                                                              acc[mf][nf], 0, 0, 0);
  }

  const long row0 = (long)b * LL + mt * 128 + wr * 64;
  const int col0 = wc * 64;
  #pragma unroll
  for (int mf = 0; mf < 4; ++mf)
    #pragma unroll
    for (int nf = 0; nf < 4; ++nf) {
      const long r = row0 + mf * 16 + l15;
      const int c = col0 + nf * 16 + lhi * 4;
      u16x4 v;
      #pragma unroll
      for (int i = 0; i < 4; ++i) v[i] = f2bf(acc[mf][nf][i]);
      *(u16x4*)(memB + r * KD + c) = v;
    }
}

// ---------------------------------------------------------------
// K5: q GEMM, B-resident + DOUBLE-BUFFERED A. 256 blocks (1/CU),
// block = (b, nt). B panel 64 KB resident; A tiles BM=128 (32 KB)
// ping-pong A0/A1 over 16 mt gens. Per gen: stage(t+1) issued at TOP
// (loads get a full generation to land) -> compute from A[t&1] ->
// 16 stores -> vmcnt(16) [= exactly this gen's stores left in flight;
// in-order retire => loads(t+1) + stores(t-1) drained] -> s_barrier.
// One barrier + one counted wait per gen; stores never drained in-loop.
// ---------------------------------------------------------------
__global__ __launch_bounds__(512, 2) void gemm_q(const unsigned short* __restrict__ A,
                                                 const unsigned short* __restrict__ Bm,
                                                 float* __restrict__ C) {
  __shared__ unsigned short ldsB[32768];   // B panel 64 KB (resident)
  __shared__ unsigned short ldsA0[16384];  // A tile 32 KB (ping)
  __shared__ unsigned short ldsA1[16384];  // A tile 32 KB (pong)

  // 256 blocks: xcd = bid % 8 owns 32 logical = 4 whole batches
  const int lg = (blockIdx.x & 7) * 32 + (blockIdx.x >> 3);
  const int nt = lg & 7;
  const int b = lg >> 3;

  const int tid = threadIdx.x;
  const int lane = tid & 63, w = tid >> 6;     // 8 waves
  const int l15 = lane & 15, lhi = lane >> 4;
  const int wrM = w >> 2;                      // 0..1 : 64-row half
  const int wcN = w & 3;                       // 0..3 : 64-col block

  const unsigned short* gB = Bm + ((long)b * LL + nt * 256) * KD;
  const unsigned short* gAb = A + (long)b * LL * KD;

  // ---- prologue: stage B panel (64 KB) + A(0) (32 KB); full drain ----
  #pragma unroll
  for (int i = 0; i < 8; ++i) {
    const int addr = i * 8192 + tid * 16;
    const int row = addr >> 8;
    const int src = addr ^ ((row & 7) << 4);
    stage16((const char*)gB + src, (char*)ldsB + addr);
  }
  #pragma unroll
  for (int i = 0; i < 4; ++i) {
    const int addr = i * 8192 + tid * 16;
    const int row = addr >> 8;
    const int src = addr ^ ((row & 7) << 4);
    stage16((const char*)gAb + src, (char*)ldsA0 + addr);
  }
  asm volatile("s_waitcnt vmcnt(0)" ::: "memory");
  __builtin_amdgcn_s_barrier();
  __builtin_amdgcn_sched_barrier(0);

  const int col0 = nt * 256 + wcN * 64;

  auto gen = [&](int mt, const unsigned short* abuf, unsigned short* nbuf) {
    // ---- issue next-gen A stage FIRST (oldest in VM queue) ----
    if (mt < 15) {
      const char* gA = (const char*)(gAb + (long)(mt + 1) * 128 * KD);
      #pragma unroll
      for (int i = 0; i < 4; ++i) {
        const int addr = i * 8192 + tid * 16;
        const int row = addr >> 8;
        const int src = addr ^ ((row & 7) << 4);
        stage16(gA + src, (char*)nbuf + addr);
      }
    }
    __builtin_amdgcn_sched_barrier(0);

    // ---- compute 128x256 from abuf + ldsB ----
    f32x4 acc[4][4];
    #pragma unroll
    for (int i = 0; i < 4; ++i)
      #pragma unroll
      for (int j = 0; j < 4; ++j) acc[i][j] = f32x4{0.f, 0.f, 0.f, 0.f};

    #pragma unroll
    for (int ks = 0; ks < 4; ++ks) {
      const int kb = (ks * 32 + lhi * 8) * 2;
      bf16x8 av[4], bv[4];
      #pragma unroll
      for (int mf = 0; mf < 4; ++mf) {
        const int row = wrM * 64 + mf * 16 + l15;
        const int byte = (row * 256 + kb) ^ ((row & 7) << 4);
        av[mf] = *(const bf16x8*)((const char*)abuf + byte);
      }
      #pragma unroll
      for (int nf = 0; nf < 4; ++nf) {
        const int row = wcN * 64 + nf * 16 + l15;
        const int byte = (row * 256 + kb) ^ ((row & 7) << 4);
        bv[nf] = *(const bf16x8*)((const char*)ldsB + byte);
      }
      // swapped operands: lane&15 = out row, (lane>>4)*4+reg = out col
      #pragma unroll
      for (int mf = 0; mf < 4; ++mf)
        #pragma unroll
        for (int nf = 0; nf < 4; ++nf)
          acc[mf][nf] = __builtin_amdgcn_mfma_f32_16x16x32_bf16(bv[nf], av[mf],
                                                                acc[mf][nf], 0, 0, 0);
    }

    // ---- 16 cached dwordx4 stores (fire and forget) ----
    const long row0 = (long)b * LL + mt * 128 + wrM * 64;
    #pragma unroll
    for (int mf = 0; mf < 4; ++mf)
      #pragma unroll
      for (int nf = 0; nf < 4; ++nf) {
        const long r = row0 + mf * 16 + l15;
        const int c = col0 + nf * 16 + lhi * 4;
        *(f32x4*)(C + r * LL + c) = acc[mf][nf];
      }

    // ---- end-of-gen: drain loads(t+1)+stores(t-1), keep stores(t) ----
    if (mt < 15) {
      asm volatile("s_waitcnt vmcnt(16)" ::: "memory");
      __builtin_amdgcn_sched_barrier(0);
      __builtin_amdgcn_s_barrier();
      __builtin_amdgcn_sched_barrier(0);
    }
  };

  #pragma unroll 1
  for (int mt2 = 0; mt2 < 8; ++mt2) {
    gen(2 * mt2, ldsA0, ldsA1);
    gen(2 * mt2 + 1, ldsA1, ldsA0);
  }
}

// ---------------------------------------------------------------
// launch
// ---------------------------------------------------------------
extern "C" void kernel_launch(void* const* d_in, const int* in_sizes, int n_in,
                              void* d_out, int out_size, void* d_ws, size_t ws_size,
                              hipStream_t stream) {
  const float* key = (const float*)d_in[0];  // (32, 2048, 128)
  const float* val = (const float*)d_in[1];  // (32, 256, 128)
  const float* wts = (const float*)d_in[2];  // (128, 64, 256)
  float* out = (float*)d_out;                // (32, 2048, 2048) fp32

  // workspace layout (total ~33.1 MiB)
  char* ws = (char*)d_ws;
  float* W2 = (float*)ws;                                        // 128 KiB
  unsigned short* Tt = (unsigned short*)(ws + 131072);           // 1 MiB
  unsigned short* keyB = (unsigned short*)(ws + 131072 + 1048576);            // 16 MiB
  unsigned short* memB = (unsigned short*)(ws + 131072 + 1048576 + 16777216); // 16 MiB

  fold_w<<<128, 256, 0, stream>>>(wts, W2);
  compute_t<<<dim3(16, NB), 128, 0, stream>>>(W2, val, Tt);
  gemm_mem_f<<<16 * NB, 256, 0, stream>>>(key, Tt, keyB, memB);
  gemm_q<<<8 * NB, 512, 0, stream>>>(keyB, memB, out);
}